// Round 5
// baseline (16182.516 us; speedup 1.0000x reference)
//
#include <hip/hip_runtime.h>

// Persistent batched-GRU kernel for MI355X (gfx950), round 5.
// B=16384, T=1024, H=256. 256 blocks x 1024 threads (16 waves, 1 block/CU).
// Each block owns 64 batch rows for all 1024 steps; wave w owns matched gate
// columns c=w*16+r16 (+256,+512) so r,z,n align in its own accumulators.
// Round-5 changes vs round 4:
//  - weights moved from d_ws (suspected fine-grained/host-coherent -> L2
//    bypass; FETCH_SIZE was 45.6 GB vs ~0.2 GB ideal) into a __device__
//    module global (coarse-grained, L2-cacheable).
//  - b-frag addresses anchored mid-range: all 8 k-step loads are one base
//    + signed imm13 offset (ks*1024-3584 in [-3584,+3584]) -> no addr VALU.
//  - b-frag prefetch deepened to distance 2 (covers ~L2-hit latency).
// Carried: 1 barrier/step (double-buffered h), rcp-sigmoid, DPP out-reduce
// (converges in lane r16==15), transposed x_buf, chunked x/out staging.

#define B_TOTAL 16384
#define T_LEN   1024
#define M_ROWS  64
#define NBLOCKS (B_TOTAL / M_ROWS)      // 256 -> 1 block/CU
#define NTHREADS 1024                   // 16 waves
#define LDSW    264                     // h row stride in shorts (16B-aligned rows)
#define TCH     32                      // t-chunk length
#define NCH     (T_LEN / TCH)
#define XSTR    68                      // x_buf t-row stride (floats)
#define OSTR    37                      // out_buf row stride (floats)

typedef short short8 __attribute__((ext_vector_type(8)));
typedef float f32x4  __attribute__((ext_vector_type(4)));

__device__ unsigned short g_wsw[196608];   // swizzled bf16 W_hh (384 KB, module global)

__device__ __forceinline__ unsigned short f2b(float f) {
  unsigned u = __builtin_bit_cast(unsigned, f);
  u += 0x7fffu + ((u >> 16) & 1u);
  return (unsigned short)(u >> 16);
}
__device__ __forceinline__ float fast_sig(float x) {
  return __builtin_amdgcn_rcpf(1.0f + __expf(-x));   // v_exp + v_rcp, no div seq
}
__device__ __forceinline__ float fast_tanh(float x) {
  return 2.0f * fast_sig(2.0f * x) - 1.0f;
}
// sum over a 16-lane DPP row; result valid in the LAST lane of the row (r16==15)
__device__ __forceinline__ float dpp_red16(float v) {
  int x = __builtin_bit_cast(int, v);
  v += __builtin_bit_cast(float, __builtin_amdgcn_update_dpp(0, x, 0x118, 0xF, 0xF, true)); // row_shr:8
  x = __builtin_bit_cast(int, v);
  v += __builtin_bit_cast(float, __builtin_amdgcn_update_dpp(0, x, 0x114, 0xF, 0xF, true)); // row_shr:4
  x = __builtin_bit_cast(int, v);
  v += __builtin_bit_cast(float, __builtin_amdgcn_update_dpp(0, x, 0x112, 0xF, 0xF, true)); // row_shr:2
  x = __builtin_bit_cast(int, v);
  v += __builtin_bit_cast(float, __builtin_amdgcn_update_dpp(0, x, 0x111, 0xF, 0xF, true)); // row_shr:1
  return v;
}

// Swizzle W_hh (768x256 f32 row-major) into fragment-major bf16:
// dst[((nt*8 + ks)*64 + lane)*8 + e] = bf16(W[nt*16 + (lane&15)][ks*32 + (lane>>4)*8 + e])
__global__ void prep_w(const float* __restrict__ w_hh) {
  int tid  = blockIdx.x * 256 + threadIdx.x;     // 196608 total
  int e    = tid & 7;
  int lane = (tid >> 3) & 63;
  int ks   = (tid >> 9) & 7;
  int nt   = tid >> 12;
  int row  = nt * 16 + (lane & 15);
  int col  = ks * 32 + (lane >> 4) * 8 + e;
  g_wsw[tid] = f2b(w_hh[row * 256 + col]);
}

__global__ __launch_bounds__(NTHREADS, 4) void gru_kernel(
    const float* __restrict__ x,
    const float* __restrict__ w_ih,
    const float* __restrict__ b_ih,
    const float* __restrict__ b_hh,
    const float* __restrict__ w_out,
    const float* __restrict__ b_out,
    float* __restrict__ out)
{
  __shared__ unsigned short h_lds[2][M_ROWS * LDSW];   // 2 x 33 KB (double-buffered h)
  __shared__ float x_buf[2][TCH * XSTR];               // 2 x 8.5 KB, [t][row]
  __shared__ float out_buf[2][M_ROWS * OSTR];          // 2 x 9.3 KB, [row][t]
  __shared__ float out_part[2][16][M_ROWS];            // 2 x 4 KB

  const int tid  = threadIdx.x;
  const int w    = tid >> 6;        // wave 0..15
  const int lane = tid & 63;
  const int r16  = lane & 15;
  const int q    = lane >> 4;
  const long base = (long)blockIdx.x * M_ROWS;

  for (int i = tid; i < M_ROWS * LDSW; i += NTHREADS) h_lds[0][i] = 0;  // h0 = 0

  const int c = w * 16 + r16;       // this wave's matched column
  const float wi_r  = w_ih[c];
  const float wi_z  = w_ih[256 + c];
  const float wi_n  = w_ih[512 + c];
  const float bt_r  = b_ih[c]       + b_hh[c];
  const float bt_z  = b_ih[256 + c] + b_hh[256 + c];
  const float bih_n = b_ih[512 + c];
  const float bhh_n = b_hh[512 + c];
  const float wo    = w_out[c];
  const float bo    = b_out[0];
  const f32x4 zero4 = {0.f, 0.f, 0.f, 0.f};

  f32x4 h_reg[4];                   // C layout: row = mt*16 + q*4 + i, col = c
#pragma unroll
  for (int mt = 0; mt < 4; ++mt) h_reg[mt] = zero4;

  // B-frag anchored base: frag (g, ks) at ((g*16 + w)*8 + ks)*512 + lane*8.
  // Anchor +1792 els so ks*512-1792 spans [-1792,+1792] els = +/-3584 B (imm13).
  const unsigned short* bp[3];
#pragma unroll
  for (int g = 0; g < 3; ++g)
    bp[g] = g_wsw + ((long)((g * 16 + w) * 8) * 64 + lane) * 8 + 1792;

  const int row64 = tid >> 4;            // 0..63 (refill/flush role)
  const int ko2   = (tid & 15) * 2;      // t-pair within chunk

  // prefill x chunk 0 (transposed into x_buf[0])
  {
    float2 v = *(const float2*)&x[(base + row64) * T_LEN + ko2];
    x_buf[0][(ko2 + 0) * XSTR + row64] = v.x;
    x_buf[0][(ko2 + 1) * XSTR + row64] = v.y;
  }
  __syncthreads();

  // one GRU step: reads h_lds[rp], x_buf[xp]; writes h_lds[rp^1], out_part[rp]
  auto gru_step = [&](int tr, int rp, int xp) {
    f32x4 acc[4][3];
#pragma unroll
    for (int mt = 0; mt < 4; ++mt)
#pragma unroll
      for (int g = 0; g < 3; ++g) acc[mt][g] = zero4;

    // rolling 2-deep b-frag prefetch (fully unrolled loop renames registers)
    short8 b0[3], b1[3];
#pragma unroll
    for (int g = 0; g < 3; ++g) {
      b0[g] = *(const short8*)(bp[g] + (0 * 512 - 1792));
      b1[g] = *(const short8*)(bp[g] + (1 * 512 - 1792));
    }
    const unsigned short* hb = &h_lds[rp][0];

#pragma unroll
    for (int ks = 0; ks < 8; ++ks) {
      short8 bc[3];
#pragma unroll
      for (int g = 0; g < 3; ++g) {
        bc[g] = b0[g];
        b0[g] = b1[g];
        if (ks < 6) b1[g] = *(const short8*)(bp[g] + ((ks + 2) * 512 - 1792));
      }
      short8 a[4];
#pragma unroll
      for (int mt = 0; mt < 4; ++mt)
        a[mt] = *(const short8*)&hb[(mt * 16 + r16) * LDSW + ks * 32 + q * 8];
#pragma unroll
      for (int g = 0; g < 3; ++g)
#pragma unroll
        for (int mt = 0; mt < 4; ++mt)
          acc[mt][g] = __builtin_amdgcn_mfma_f32_16x16x32_bf16(a[mt], bc[g], acc[mt][g], 0, 0, 0);
    }

    // gates + h publish + out partial (writes to h_lds[rp^1] are safe
    // pre-barrier: all reads of that buffer finished before the previous barrier)
    unsigned short* hw = &h_lds[rp ^ 1][0];
#pragma unroll
    for (int mt = 0; mt < 4; ++mt) {
      f32x4 xv = *(const f32x4*)&x_buf[xp][tr * XSTR + mt * 16 + q * 4];  // broadcast b128
      f32x4 vo;
#pragma unroll
      for (int i = 0; i < 4; ++i) {
        float rg = fast_sig(acc[mt][0][i] + xv[i] * wi_r + bt_r);
        float zg = fast_sig(acc[mt][1][i] + xv[i] * wi_z + bt_z);
        float ng = fast_tanh(xv[i] * wi_n + bih_n + rg * (acc[mt][2][i] + bhh_n));
        float hn = (1.0f - zg) * ng + zg * h_reg[mt][i];
        h_reg[mt][i] = hn;
        hw[(mt * 16 + q * 4 + i) * LDSW + c] = f2b(hn);
        vo[i] = fmaxf(hn, 0.0f) * wo;
      }
#pragma unroll
      for (int i = 0; i < 4; ++i) vo[i] = dpp_red16(vo[i]);
      if (r16 == 15) {   // row_shr reduction converges into the LAST lane
#pragma unroll
        for (int i = 0; i < 4; ++i)
          out_part[rp][w][mt * 16 + q * 4 + i] = vo[i];
      }
    }
  };

#pragma unroll 1
  for (int tc = 0; tc < NCH; ++tc) {
    const int xp = tc & 1;
    const int ob = tc & 1;
#pragma unroll 1
    for (int tr = 0; tr < TCH; tr += 2) {
      // ---- even step (rp = 0)
      gru_step(tr, 0, xp);
      if (tr == 0 && tc + 1 < NCH) {    // refill next x chunk (disjoint buffer)
        float2 v = *(const float2*)&x[(base + row64) * T_LEN + (tc + 1) * TCH + ko2];
        x_buf[xp ^ 1][(ko2 + 0) * XSTR + row64] = v.x;
        x_buf[xp ^ 1][(ko2 + 1) * XSTR + row64] = v.y;
      }
      __syncthreads();
      if (tid < M_ROWS) {               // finalize out for this step
        float o = bo;
#pragma unroll
        for (int ww = 0; ww < 16; ++ww) o += out_part[0][ww][tid];
        out_buf[ob][tid * OSTR + tr] = o;
      }
      if (tr == 0 && tc > 0) {          // flush previous chunk (coalesced float2)
        float2 v;
        v.x = out_buf[ob ^ 1][row64 * OSTR + ko2];
        v.y = out_buf[ob ^ 1][row64 * OSTR + ko2 + 1];
        *(float2*)&out[(base + row64) * T_LEN + (tc - 1) * TCH + ko2] = v;
      }
      // ---- odd step (rp = 1)
      gru_step(tr + 1, 1, xp);
      __syncthreads();
      if (tid < M_ROWS) {
        float o = bo;
#pragma unroll
        for (int ww = 0; ww < 16; ++ww) o += out_part[1][ww][tid];
        out_buf[ob][tid * OSTR + tr + 1] = o;
      }
    }
  }
  __syncthreads();
  {  // flush final chunk
    float2 v;
    v.x = out_buf[(NCH - 1) & 1][row64 * OSTR + ko2];
    v.y = out_buf[(NCH - 1) & 1][row64 * OSTR + ko2 + 1];
    *(float2*)&out[(base + row64) * T_LEN + (NCH - 1) * TCH + ko2] = v;
  }
}

extern "C" void kernel_launch(void* const* d_in, const int* in_sizes, int n_in,
                              void* d_out, int out_size, void* d_ws, size_t ws_size,
                              hipStream_t stream) {
  const float* x     = (const float*)d_in[0];
  const float* w_ih  = (const float*)d_in[1];
  const float* w_hh  = (const float*)d_in[2];
  const float* b_ih  = (const float*)d_in[3];
  const float* b_hh  = (const float*)d_in[4];
  const float* w_out = (const float*)d_in[5];
  const float* b_out = (const float*)d_in[6];
  float* out = (float*)d_out;

  prep_w<<<768, 256, 0, stream>>>(w_hh);
  gru_kernel<<<NBLOCKS, NTHREADS, 0, stream>>>(x, w_ih, b_ih, b_hh, w_out, b_out, out);
}

// Round 6
// 15048.973 us; speedup vs baseline: 1.0753x; 1.0753x over previous
//
#include <hip/hip_runtime.h>

// Persistent batched-GRU kernel for MI355X (gfx950), round 6.
// B=16384, T=1024, H=256. 256 blocks x 1024 threads (16 waves, 1 block/CU).
// Each block owns 64 batch rows for all 1024 steps; wave w owns matched gate
// columns c=w*16+r16 (+256,+512) so r,z,n align in its own accumulators.
// Round-6 changes vs round 5 (which regressed: K-loop ring copies serialized
// MFMA issue; full vmcnt(0) drain at every barrier left L2 idle during gates):
//  - copy-free parity ring bf0/bf1 selected by compile-time (ks&1) in the
//    fully unrolled K-loop -> SSA renaming, zero v_mov chains.
//  - cross-barrier weight prefetch: ks=0/1 frags for the next step issued
//    before the gate phase (weights are step-invariant), kept in flight
//    through an lgkmcnt-only barrier (asm s_waitcnt lgkmcnt(0); s_barrier).
//    LDS ordering is preserved; the vmcnt(0) drain of __syncthreads is not
//    needed for correctness (only h_lds/x_buf/out_part cross the barrier).
//  - sigma row-swizzle sigma(r)=(r&3)*4+(r>>2) on h_lds rows (write AND read)
//    breaks the 4-row/16-bank aliasing of the scalar b16 h-publishes
//    (SQ_LDS_BANK_CONFLICT 5.38e8 ~= 2.1k cyc/block/step in r4/r5).
// Carried: L2-cached module-global weights, anchored imm13 b-frag addressing,
// 1 barrier/step (double-buffered h), rcp-sigmoid, DPP out-reduce (lane 15),
// transposed x_buf, chunked x/out staging.

#define B_TOTAL 16384
#define T_LEN   1024
#define M_ROWS  64
#define NBLOCKS (B_TOTAL / M_ROWS)      // 256 -> 1 block/CU
#define NTHREADS 1024                   // 16 waves
#define LDSW    264                     // h row stride in shorts (16B-aligned rows)
#define TCH     32                      // t-chunk length
#define NCH     (T_LEN / TCH)
#define XSTR    68                      // x_buf t-row stride (floats)
#define OSTR    37                      // out_buf row stride (floats)

typedef short short8 __attribute__((ext_vector_type(8)));
typedef float f32x4  __attribute__((ext_vector_type(4)));

__device__ unsigned short g_wsw[196608];   // swizzled bf16 W_hh (384 KB, L2-cacheable)

__device__ __forceinline__ unsigned short f2b(float f) {
  unsigned u = __builtin_bit_cast(unsigned, f);
  u += 0x7fffu + ((u >> 16) & 1u);
  return (unsigned short)(u >> 16);
}
__device__ __forceinline__ float fast_sig(float x) {
  return __builtin_amdgcn_rcpf(1.0f + __expf(-x));   // v_exp + v_rcp
}
__device__ __forceinline__ float fast_tanh(float x) {
  return 2.0f * fast_sig(2.0f * x) - 1.0f;
}
// sum over a 16-lane DPP row; result valid in the LAST lane (r16==15)
__device__ __forceinline__ float dpp_red16(float v) {
  int x = __builtin_bit_cast(int, v);
  v += __builtin_bit_cast(float, __builtin_amdgcn_update_dpp(0, x, 0x118, 0xF, 0xF, true)); // row_shr:8
  x = __builtin_bit_cast(int, v);
  v += __builtin_bit_cast(float, __builtin_amdgcn_update_dpp(0, x, 0x114, 0xF, 0xF, true)); // row_shr:4
  x = __builtin_bit_cast(int, v);
  v += __builtin_bit_cast(float, __builtin_amdgcn_update_dpp(0, x, 0x112, 0xF, 0xF, true)); // row_shr:2
  x = __builtin_bit_cast(int, v);
  v += __builtin_bit_cast(float, __builtin_amdgcn_update_dpp(0, x, 0x111, 0xF, 0xF, true)); // row_shr:1
  return v;
}
// workgroup barrier that drains LDS ops only (no vmcnt(0) -> weight prefetch
// loads stay in flight across the barrier). "memory" clobber = compiler fence.
__device__ __forceinline__ void barrier_lgkm() {
  asm volatile("s_waitcnt lgkmcnt(0)\n\ts_barrier" ::: "memory");
}

// Swizzle W_hh (768x256 f32 row-major) into fragment-major bf16:
// dst[((nt*8 + ks)*64 + lane)*8 + e] = bf16(W[nt*16 + (lane&15)][ks*32 + (lane>>4)*8 + e])
__global__ void prep_w(const float* __restrict__ w_hh) {
  int tid  = blockIdx.x * 256 + threadIdx.x;     // 196608 total
  int e    = tid & 7;
  int lane = (tid >> 3) & 63;
  int ks   = (tid >> 9) & 7;
  int nt   = tid >> 12;
  int row  = nt * 16 + (lane & 15);
  int col  = ks * 32 + (lane >> 4) * 8 + e;
  g_wsw[tid] = f2b(w_hh[row * 256 + col]);
}

// b-frag load: anchored so (ks*512-1792)*2B spans [-3584,+3584] (signed imm13)
#define BLD(g, ks) (*(const short8*)(bp[g] + ((ks) * 512 - 1792)))

__global__ __launch_bounds__(NTHREADS, 4) void gru_kernel(
    const float* __restrict__ x,
    const float* __restrict__ w_ih,
    const float* __restrict__ b_ih,
    const float* __restrict__ b_hh,
    const float* __restrict__ w_out,
    const float* __restrict__ b_out,
    float* __restrict__ out)
{
  __shared__ unsigned short h_lds[2][M_ROWS * LDSW];   // 2 x 33 KB (double-buffered h)
  __shared__ float x_buf[2][TCH * XSTR];               // [t][row]
  __shared__ float out_buf[2][M_ROWS * OSTR];          // [row][t]
  __shared__ float out_part[2][16][M_ROWS];

  const int tid  = threadIdx.x;
  const int w    = tid >> 6;        // wave 0..15
  const int lane = tid & 63;
  const int r16  = lane & 15;
  const int q    = lane >> 4;
  const int sr   = (r16 & 3) * 4 + (r16 >> 2);   // sigma(r16): swizzled LDS row
  const long base = (long)blockIdx.x * M_ROWS;

  for (int i = tid; i < M_ROWS * LDSW; i += NTHREADS) h_lds[0][i] = 0;  // h0 = 0

  const int c = w * 16 + r16;       // this wave's matched column
  const float wi_r  = w_ih[c];
  const float wi_z  = w_ih[256 + c];
  const float wi_n  = w_ih[512 + c];
  const float bt_r  = b_ih[c]       + b_hh[c];
  const float bt_z  = b_ih[256 + c] + b_hh[256 + c];
  const float bih_n = b_ih[512 + c];
  const float bhh_n = b_hh[512 + c];
  const float wo    = w_out[c];
  const float bo    = b_out[0];
  const f32x4 zero4 = {0.f, 0.f, 0.f, 0.f};

  f32x4 h_reg[4];                   // C layout: row = mt*16 + q*4 + i, col = c
#pragma unroll
  for (int mt = 0; mt < 4; ++mt) h_reg[mt] = zero4;

  const unsigned short* bp[3];
#pragma unroll
  for (int g = 0; g < 3; ++g)
    bp[g] = g_wsw + ((long)((g * 16 + w) * 8) * 64 + lane) * 8 + 1792;

  const int row64 = tid >> 4;            // 0..63 (refill/flush role)
  const int ko2   = (tid & 15) * 2;      // t-pair within chunk

  // prefill x chunk 0 (transposed into x_buf[0])
  {
    float2 v = *(const float2*)&x[(base + row64) * T_LEN + ko2];
    x_buf[0][(ko2 + 0) * XSTR + row64] = v.x;
    x_buf[0][(ko2 + 1) * XSTR + row64] = v.y;
  }

  // parity ring: bf0 holds even-ks frags, bf1 odd-ks. Initial fill ks=0,1.
  short8 bf0[3], bf1[3];
#pragma unroll
  for (int g = 0; g < 3; ++g) { bf0[g] = BLD(g, 0); bf1[g] = BLD(g, 1); }

  barrier_lgkm();

  // one GRU step: reads h_lds[rp], x_buf[xp]; writes h_lds[rp^1], out_part[rp]
  auto gru_step = [&](int tr, int rp, int xp) {
    f32x4 acc[4][3];
#pragma unroll
    for (int mt = 0; mt < 4; ++mt)
#pragma unroll
      for (int g = 0; g < 3; ++g) acc[mt][g] = zero4;

    const unsigned short* ar = &h_lds[rp][sr * LDSW + q * 8];

#pragma unroll
    for (int ks = 0; ks < 8; ++ks) {
      short8 a[4];
#pragma unroll
      for (int mt = 0; mt < 4; ++mt)
        a[mt] = *(const short8*)(ar + mt * (16 * LDSW) + ks * 32);
      if ((ks & 1) == 0) {
#pragma unroll
        for (int g = 0; g < 3; ++g)
#pragma unroll
          for (int mt = 0; mt < 4; ++mt)
            acc[mt][g] = __builtin_amdgcn_mfma_f32_16x16x32_bf16(a[mt], bf0[g], acc[mt][g], 0, 0, 0);
        if (ks < 6) {
#pragma unroll
          for (int g = 0; g < 3; ++g) bf0[g] = BLD(g, ks + 2);
        }
      } else {
#pragma unroll
        for (int g = 0; g < 3; ++g)
#pragma unroll
          for (int mt = 0; mt < 4; ++mt)
            acc[mt][g] = __builtin_amdgcn_mfma_f32_16x16x32_bf16(a[mt], bf1[g], acc[mt][g], 0, 0, 0);
        if (ks < 6) {
#pragma unroll
          for (int g = 0; g < 3; ++g) bf1[g] = BLD(g, ks + 2);
        }
      }
    }

    // prefetch next step's ks=0/1 NOW (weights are step-invariant): these 6
    // loads stay in flight through gates + the lgkm-only barrier.
#pragma unroll
    for (int g = 0; g < 3; ++g) { bf0[g] = BLD(g, 0); bf1[g] = BLD(g, 1); }

    // gates + h publish (sigma-swizzled rows) + out partial
    unsigned short* hw = &h_lds[rp ^ 1][q * LDSW + c];   // logical row q*4+i -> LDS row i*4+q
#pragma unroll
    for (int mt = 0; mt < 4; ++mt) {
      f32x4 xv = *(const f32x4*)&x_buf[xp][tr * XSTR + mt * 16 + q * 4];  // broadcast b128
      f32x4 vo;
#pragma unroll
      for (int i = 0; i < 4; ++i) {
        float rg = fast_sig(acc[mt][0][i] + xv[i] * wi_r + bt_r);
        float zg = fast_sig(acc[mt][1][i] + xv[i] * wi_z + bt_z);
        float ng = fast_tanh(xv[i] * wi_n + bih_n + rg * (acc[mt][2][i] + bhh_n));
        float hn = (1.0f - zg) * ng + zg * h_reg[mt][i];
        h_reg[mt][i] = hn;
        hw[(mt * 16 + i * 4) * LDSW] = f2b(hn);
        vo[i] = fmaxf(hn, 0.0f) * wo;
      }
#pragma unroll
      for (int i = 0; i < 4; ++i) vo[i] = dpp_red16(vo[i]);
      if (r16 == 15) {   // row_shr reduction converges into the LAST lane
#pragma unroll
        for (int i = 0; i < 4; ++i)
          out_part[rp][w][mt * 16 + q * 4 + i] = vo[i];
      }
    }
  };

#pragma unroll 1
  for (int tc = 0; tc < NCH; ++tc) {
    const int xp = tc & 1;
    const int ob = tc & 1;
#pragma unroll 1
    for (int tr = 0; tr < TCH; tr += 2) {
      // ---- even step (rp = 0)
      gru_step(tr, 0, xp);
      if (tr == 0 && tc + 1 < NCH) {    // refill next x chunk (disjoint buffer)
        float2 v = *(const float2*)&x[(base + row64) * T_LEN + (tc + 1) * TCH + ko2];
        x_buf[xp ^ 1][(ko2 + 0) * XSTR + row64] = v.x;
        x_buf[xp ^ 1][(ko2 + 1) * XSTR + row64] = v.y;
      }
      barrier_lgkm();
      if (tid < M_ROWS) {               // finalize out for this step
        float o = bo;
#pragma unroll
        for (int ww = 0; ww < 16; ++ww) o += out_part[0][ww][tid];
        out_buf[ob][tid * OSTR + tr] = o;
      }
      if (tr == 0 && tc > 0) {          // flush previous chunk (coalesced float2)
        float2 v;
        v.x = out_buf[ob ^ 1][row64 * OSTR + ko2];
        v.y = out_buf[ob ^ 1][row64 * OSTR + ko2 + 1];
        *(float2*)&out[(base + row64) * T_LEN + (tc - 1) * TCH + ko2] = v;
      }
      // ---- odd step (rp = 1)
      gru_step(tr + 1, 1, xp);
      barrier_lgkm();
      if (tid < M_ROWS) {
        float o = bo;
#pragma unroll
        for (int ww = 0; ww < 16; ++ww) o += out_part[1][ww][tid];
        out_buf[ob][tid * OSTR + tr + 1] = o;
      }
    }
  }
  barrier_lgkm();
  {  // flush final chunk
    float2 v;
    v.x = out_buf[(NCH - 1) & 1][row64 * OSTR + ko2];
    v.y = out_buf[(NCH - 1) & 1][row64 * OSTR + ko2 + 1];
    *(float2*)&out[(base + row64) * T_LEN + (NCH - 1) * TCH + ko2] = v;
  }
}

extern "C" void kernel_launch(void* const* d_in, const int* in_sizes, int n_in,
                              void* d_out, int out_size, void* d_ws, size_t ws_size,
                              hipStream_t stream) {
  const float* x     = (const float*)d_in[0];
  const float* w_ih  = (const float*)d_in[1];
  const float* w_hh  = (const float*)d_in[2];
  const float* b_ih  = (const float*)d_in[3];
  const float* b_hh  = (const float*)d_in[4];
  const float* w_out = (const float*)d_in[5];
  const float* b_out = (const float*)d_in[6];
  float* out = (float*)d_out;

  prep_w<<<768, 256, 0, stream>>>(w_hh);
  gru_kernel<<<NBLOCKS, NTHREADS, 0, stream>>>(x, w_ih, b_ih, b_hh, w_out, b_out, out);
}